// Round 9
// baseline (1366.495 us; speedup 1.0000x reference)
//
#include <hip/hip_runtime.h>
#include <stdint.h>

typedef __attribute__((ext_vector_type(8))) short short8;
typedef __attribute__((ext_vector_type(4))) float f32x4;

#define TT 512
#define LSTR 80    // sZ row stride in ushorts (40 dw)
#define XS 516     // sX row stride in floats

static __device__ __forceinline__ uint32_t f2bf_u(float f){
  union { float f; uint32_t u; } v; v.f = f;
  return (v.u + 0x7fffu + ((v.u >> 16) & 1u)) >> 16;
}
static __device__ __forceinline__ float fast_rcp(float x){ return __builtin_amdgcn_rcpf(x); }
static __device__ __forceinline__ float fast_exp2(float x){ return __builtin_amdgcn_exp2f(x); }
static __device__ __forceinline__ float sigf(float x){
  return fast_rcp(1.f + fast_exp2(-1.4426950408889634f * x));
}
static __device__ __forceinline__ float tanh_f(float x){
  return fmaf(-2.f, fast_rcp(1.f + fast_exp2(2.8853900817779268f * x)), 1.f);
}
static __device__ __forceinline__ short8 w8f32(const float* p){
  float4 a = *(const float4*)p;
  float4 b = *(const float4*)(p + 4);
  short8 r;
  r[0] = (short)f2bf_u(a.x); r[1] = (short)f2bf_u(a.y);
  r[2] = (short)f2bf_u(a.z); r[3] = (short)f2bf_u(a.w);
  r[4] = (short)f2bf_u(b.x); r[5] = (short)f2bf_u(b.y);
  r[6] = (short)f2bf_u(b.z); r[7] = (short)f2bf_u(b.w);
  return r;
}
// LDS-only barrier: waits ds ops, leaves global ops in flight.
static __device__ __forceinline__ void lds_barrier(){
  asm volatile("s_waitcnt lgkmcnt(0)" ::: "memory");
  __builtin_amdgcn_s_barrier();
}
#define MF(A,B,C) __builtin_amdgcn_mfma_f32_16x16x32_bf16((A),(B),(C),0,0,0)

// ==================== Layer 0 ====================
// 512 thr / 8 waves / 8 batches split into groups A(0-3), B(4-7).
// Wave wv owns gate rowtiles 2wv,2wv+1 (units 8wv+4rts+quad).
// One lds_barrier per (A,B) step pair; A and B chains independent -> overlap.
__global__ __launch_bounds__(512, 2) void lstm_l0(
    const float* __restrict__ x,   // [B][3][T]
    const float* __restrict__ Wih_f, const float* __restrict__ Whh_f,
    const float* __restrict__ bih_f, const float* __restrict__ bhh_f,
    const float* __restrict__ Wih_b, const float* __restrict__ Whh_b,
    const float* __restrict__ bih_b, const float* __restrict__ bhh_b,
    unsigned short* __restrict__ y0)  // [B][T][128] bf16, natural unit order
{
  const int tid = threadIdx.x;
  const int wv = tid >> 6, lane = tid & 63;
  const int quad = lane >> 4, m16 = lane & 15;
  const int dir = blockIdx.y;
  const int bbase = blockIdx.x * 8;
  const float* Wih = dir ? Wih_b : Wih_f;
  const float* Whh = dir ? Whh_b : Whh_f;
  const float* bih = dir ? bih_b : bih_f;
  const float* bhh = dir ? bhh_b : bhh_f;

  __shared__ __align__(16) unsigned short sZ[2][2][4][LSTR];  // [group][buf][batch][u]
  __shared__ __align__(16) float sX[24 * XS];

  short8 aH[2][2], aX[2];
  f32x4 biasv[2];
  const int gm = (m16 & 3) * 64 + (m16 >> 2);  // A-row: gate rho&3, unit 4rt+(rho>>2)
  #pragma unroll
  for (int i = 0; i < 2; i++){
    const int rt = 2 * wv + i;
    const int g = gm + 4 * rt;
    aH[i][0] = w8f32(Whh + g * 64 +      quad * 8);
    aH[i][1] = w8f32(Whh + g * 64 + 32 + quad * 8);
    short8 ax = {0,0,0,0,0,0,0,0};
    if (quad == 0){
      ax[0] = (short)f2bf_u(Wih[g * 3 + 0]);
      ax[1] = (short)f2bf_u(Wih[g * 3 + 1]);
      ax[2] = (short)f2bf_u(Wih[g * 3 + 2]);
    }
    aX[i] = ax;
    const int gu = 4 * rt + quad;
    #pragma unroll
    for (int r = 0; r < 4; r++) biasv[i][r] = bih[r * 64 + gu] + bhh[r * 64 + gu];
  }

  for (int idx = tid; idx < 2 * 2 * 4 * LSTR; idx += 512)
    ((unsigned short*)sZ)[idx] = 0;
  for (int i4 = tid; i4 < 24 * 128; i4 += 512){
    const int row = i4 >> 7, t4 = (i4 & 127) * 4;
    *(float4*)&sX[row * XS + t4] = *(const float4*)(x + (size_t)bbase * 1536 + row * 512 + t4);
  }
  __syncthreads();

  const int gb  = m16 & 3;             // batch within group
  const int rts = (m16 >> 2) & 1;      // rowtile this lane post-processes
  const int u   = 8 * wv + 4 * rts + quad;
  const int xrA = 3 * gb, xrB = 3 * (gb + 4);
  float cA = 0.f, cB = 0.f;

  f32x4 accXA[2], accXB[2];
  {
    const int t0 = dir ? (TT - 1) : 0;
    short8 bxA = {0,0,0,0,0,0,0,0}, bxB = {0,0,0,0,0,0,0,0};
    if (quad == 0){
      bxA[0] = (short)f2bf_u(sX[xrA * XS + t0]);
      bxA[1] = (short)f2bf_u(sX[(xrA + 1) * XS + t0]);
      bxA[2] = (short)f2bf_u(sX[(xrA + 2) * XS + t0]);
      bxB[0] = (short)f2bf_u(sX[xrB * XS + t0]);
      bxB[1] = (short)f2bf_u(sX[(xrB + 1) * XS + t0]);
      bxB[2] = (short)f2bf_u(sX[(xrB + 2) * XS + t0]);
    }
    accXA[0] = MF(aX[0], bxA, biasv[0]); accXA[1] = MF(aX[1], bxA, biasv[1]);
    accXB[0] = MF(aX[0], bxB, biasv[0]); accXB[1] = MF(aX[1], bxB, biasv[1]);
  }

  const int sg = wv >> 2, sb = wv & 3;   // this wave stores batch sb of group sg

  for (int s = 0; s < TT; s++){
    const int p = s & 1, p1 = p ^ 1;
    const int t = dir ? (TT - 1 - s) : s;

    // coalesced y0 store of h(s-1) (stable in buf p until interval s+1 ends)
    if (s > 0 && lane < 8){
      const int tprev = dir ? (TT - s) : (s - 1);
      short8 v = *(const short8*)&sZ[sg][p][sb][lane * 8];
      *(short8*)(y0 + ((size_t)(bbase + 4 * sg + sb) * TT + tprev) * 128 + dir * 64 + lane * 8) = v;
    }

    // ---- group A step ----
    {
      short8 bh0 = *(const short8*)&sZ[0][p][gb][     quad * 8];
      short8 bh1 = *(const short8*)&sZ[0][p][gb][32 + quad * 8];
      f32x4 a0, a1;
      a0 = MF(aH[0][0], bh0, accXA[0]);  a1 = MF(aH[1][0], bh0, accXA[1]);
      a0 = MF(aH[0][1], bh1, a0);        a1 = MF(aH[1][1], bh1, a1);
      f32x4 g4 = rts ? a1 : a0;
      float ip = sigf(g4[0]), fp = sigf(g4[1]), gp = tanh_f(g4[2]), op = sigf(g4[3]);
      cA = fmaf(fp, cA, ip * gp);
      float h = op * tanh_f(cA);
      if (m16 < 8) sZ[0][p1][gb][u] = (unsigned short)f2bf_u(h);
    }
    // ---- group B step ----
    {
      short8 bh0 = *(const short8*)&sZ[1][p][gb][     quad * 8];
      short8 bh1 = *(const short8*)&sZ[1][p][gb][32 + quad * 8];
      f32x4 a0, a1;
      a0 = MF(aH[0][0], bh0, accXB[0]);  a1 = MF(aH[1][0], bh0, accXB[1]);
      a0 = MF(aH[0][1], bh1, a0);        a1 = MF(aH[1][1], bh1, a1);
      f32x4 g4 = rts ? a1 : a0;
      float ip = sigf(g4[0]), fp = sigf(g4[1]), gp = tanh_f(g4[2]), op = sigf(g4[3]);
      cB = fmaf(fp, cB, ip * gp);
      float h = op * tanh_f(cB);
      if (m16 < 8) sZ[1][p1][gb][u] = (unsigned short)f2bf_u(h);
    }
    // ---- shadows: accX for s+1 ----
    {
      const int sn = (s + 1 < TT) ? (s + 1) : s;
      const int tn = dir ? (TT - 1 - sn) : sn;
      short8 bxA = {0,0,0,0,0,0,0,0}, bxB = {0,0,0,0,0,0,0,0};
      if (quad == 0){
        bxA[0] = (short)f2bf_u(sX[xrA * XS + tn]);
        bxA[1] = (short)f2bf_u(sX[(xrA + 1) * XS + tn]);
        bxA[2] = (short)f2bf_u(sX[(xrA + 2) * XS + tn]);
        bxB[0] = (short)f2bf_u(sX[xrB * XS + tn]);
        bxB[1] = (short)f2bf_u(sX[(xrB + 1) * XS + tn]);
        bxB[2] = (short)f2bf_u(sX[(xrB + 2) * XS + tn]);
      }
      accXA[0] = MF(aX[0], bxA, biasv[0]); accXA[1] = MF(aX[1], bxA, biasv[1]);
      accXB[0] = MF(aX[0], bxB, biasv[0]); accXB[1] = MF(aX[1], bxB, biasv[1]);
    }
    lds_barrier();
  }
  // final y0 store: h(TT-1) sits in buf 0
  if (lane < 8){
    const int tl = dir ? 0 : (TT - 1);
    short8 v = *(const short8*)&sZ[sg][0][sb][lane * 8];
    *(short8*)(y0 + ((size_t)(bbase + 4 * sg + sb) * TT + tl) * 128 + dir * 64 + lane * 8) = v;
  }
}

// ==================== Layer 1 ====================
__global__ __launch_bounds__(512, 2) void lstm_l1(
    const unsigned short* __restrict__ y0,  // [B][T][128] bf16
    const float* __restrict__ Wih_f, const float* __restrict__ Whh_f,
    const float* __restrict__ bih_f, const float* __restrict__ bhh_f,
    const float* __restrict__ Wih_b, const float* __restrict__ Whh_b,
    const float* __restrict__ bih_b, const float* __restrict__ bhh_b,
    float* __restrict__ hT)                 // [B][128] fp32
{
  const int tid = threadIdx.x;
  const int wv = tid >> 6, lane = tid & 63;
  const int quad = lane >> 4, m16 = lane & 15;
  const int dir = blockIdx.y;
  const int bbase = blockIdx.x * 8;
  const float* Wih = dir ? Wih_b : Wih_f;
  const float* Whh = dir ? Whh_b : Whh_f;
  const float* bih = dir ? bih_b : bih_f;
  const float* bhh = dir ? bhh_b : bhh_f;

  __shared__ __align__(16) unsigned short sZ[2][2][4][LSTR];

  short8 aY[2][4], aH[2][2];
  f32x4 biasv[2];
  const int gm = (m16 & 3) * 64 + (m16 >> 2);
  #pragma unroll
  for (int i = 0; i < 2; i++){
    const int rt = 2 * wv + i;
    const int g = gm + 4 * rt;
    #pragma unroll
    for (int kt = 0; kt < 4; kt++)
      aY[i][kt] = w8f32(Wih + g * 128 + kt * 32 + quad * 8);
    aH[i][0] = w8f32(Whh + g * 64 +      quad * 8);
    aH[i][1] = w8f32(Whh + g * 64 + 32 + quad * 8);
    const int gu = 4 * rt + quad;
    #pragma unroll
    for (int r = 0; r < 4; r++) biasv[i][r] = bih[r * 64 + gu] + bhh[r * 64 + gu];
  }

  for (int idx = tid; idx < 2 * 2 * 4 * LSTR; idx += 512)
    ((unsigned short*)sZ)[idx] = 0;
  __syncthreads();

  const int gb  = m16 & 3;
  const int rts = (m16 >> 2) & 1;
  const int u   = 8 * wv + 4 * rts + quad;
  const size_t browA = (size_t)(bbase + gb) * TT;
  const size_t browB = (size_t)(bbase + 4 + gb) * TT;
  const int coff = quad * 8;
  float cA = 0.f, cB = 0.f;

  short8 FA[2][4], FB[2][4];
  #define LOADF(DST, BROW, S) do { \
      int sg_ = (S); if (sg_ > TT - 1) sg_ = TT - 1; \
      const int tg = dir ? (TT - 1 - sg_) : sg_; \
      const unsigned short* yb = y0 + ((BROW) + tg) * 128; \
      DST[0] = *(const short8*)(yb +      coff); \
      DST[1] = *(const short8*)(yb + 32 + coff); \
      DST[2] = *(const short8*)(yb + 64 + coff); \
      DST[3] = *(const short8*)(yb + 96 + coff); \
    } while(0)
  #define ACCY(OUT, FS) do { \
      _Pragma("unroll") \
      for (int i = 0; i < 2; i++){ \
        f32x4 a = biasv[i]; \
        a = MF(aY[i][0], FS[0], a); a = MF(aY[i][1], FS[1], a); \
        a = MF(aY[i][2], FS[2], a); a = MF(aY[i][3], FS[3], a); \
        OUT[i] = a; \
      } \
    } while(0)

  f32x4 accYA[2], accYB[2];
  LOADF(FA[0], browA, 0); LOADF(FB[0], browB, 0);
  ACCY(accYA, FA[0]);     ACCY(accYB, FB[0]);
  LOADF(FA[1], browA, 1); LOADF(FB[1], browB, 1);
  LOADF(FA[0], browA, 2); LOADF(FB[0], browB, 2);

#define L1STEP(S, SLOT) do { \
    const int p = (S) & 1, p1 = p ^ 1; \
    /* group A */ \
    { \
      short8 bh0 = *(const short8*)&sZ[0][p][gb][     coff]; \
      short8 bh1 = *(const short8*)&sZ[0][p][gb][32 + coff]; \
      f32x4 a0, a1; \
      a0 = MF(aH[0][0], bh0, accYA[0]);  a1 = MF(aH[1][0], bh0, accYA[1]); \
      a0 = MF(aH[0][1], bh1, a0);        a1 = MF(aH[1][1], bh1, a1); \
      f32x4 g4 = rts ? a1 : a0; \
      float ip = sigf(g4[0]), fp = sigf(g4[1]), gp = tanh_f(g4[2]), op = sigf(g4[3]); \
      cA = fmaf(fp, cA, ip * gp); \
      float h = op * tanh_f(cA); \
      if (m16 < 8){ \
        sZ[0][p1][gb][u] = (unsigned short)f2bf_u(h); \
        if ((S) == TT - 1) hT[(size_t)(bbase + gb) * 128 + dir * 64 + u] = h; \
      } \
    } \
    /* group B */ \
    { \
      short8 bh0 = *(const short8*)&sZ[1][p][gb][     coff]; \
      short8 bh1 = *(const short8*)&sZ[1][p][gb][32 + coff]; \
      f32x4 a0, a1; \
      a0 = MF(aH[0][0], bh0, accYB[0]);  a1 = MF(aH[1][0], bh0, accYB[1]); \
      a0 = MF(aH[0][1], bh1, a0);        a1 = MF(aH[1][1], bh1, a1); \
      f32x4 g4 = rts ? a1 : a0; \
      float ip = sigf(g4[0]), fp = sigf(g4[1]), gp = tanh_f(g4[2]), op = sigf(g4[3]); \
      cB = fmaf(fp, cB, ip * gp); \
      float h = op * tanh_f(cB); \
      if (m16 < 8){ \
        sZ[1][p1][gb][u] = (unsigned short)f2bf_u(h); \
        if ((S) == TT - 1) hT[(size_t)(bbase + 4 + gb) * 128 + dir * 64 + u] = h; \
      } \
    } \
    /* shadows: accY for S+1 from slot, then refill slot for S+3 */ \
    ACCY(accYA, FA[SLOT]); ACCY(accYB, FB[SLOT]); \
    LOADF(FA[SLOT], browA, (S) + 3); \
    LOADF(FB[SLOT], browB, (S) + 3); \
    lds_barrier(); \
  } while(0)

  for (int s = 0; s < TT; s += 2){
    L1STEP(s,     1);   // uses FA[1]=y(t(s+1))
    L1STEP(s + 1, 0);   // uses FA[0]=y(t(s+2))
  }
#undef L1STEP
#undef ACCY
#undef LOADF
}

// ==================== FC head ====================
__global__ __launch_bounds__(256, 1) void fc_kernel(
    const float* __restrict__ hT,
    const float* __restrict__ w1, const float* __restrict__ b1,
    const float* __restrict__ w2, const float* __restrict__ b2,
    float* __restrict__ out)
{
  __shared__ float sh[4][64];
  const int wave = threadIdx.x >> 6, lane = threadIdx.x & 63;
  const int b = blockIdx.x * 4 + wave;
  float acc = b1[lane];
  const float* hrow = hT + (size_t)b * 128;
  #pragma unroll
  for (int k = 0; k < 128; k += 4){
    float4 h4 = *(const float4*)(hrow + k);
    float4 w4 = *(const float4*)(w1 + lane * 128 + k);
    acc = fmaf(w4.x, h4.x, acc);
    acc = fmaf(w4.y, h4.y, acc);
    acc = fmaf(w4.z, h4.z, acc);
    acc = fmaf(w4.w, h4.w, acc);
  }
  sh[wave][lane] = fmaxf(acc, 0.f);
  __syncthreads();
  if (lane < 2){
    float a = b2[lane];
    #pragma unroll
    for (int k = 0; k < 64; k++) a = fmaf(w2[lane * 64 + k], sh[wave][k], a);
    out[(size_t)b * 2 + lane] = a;
  }
}

extern "C" void kernel_launch(void* const* d_in, const int* in_sizes, int n_in,
                              void* d_out, int out_size, void* d_ws, size_t ws_size,
                              hipStream_t stream){
  (void)in_sizes; (void)n_in; (void)out_size; (void)ws_size;
  const float* x     = (const float*)d_in[0];
  const float* Wih0f = (const float*)d_in[1];
  const float* Whh0f = (const float*)d_in[2];
  const float* bih0f = (const float*)d_in[3];
  const float* bhh0f = (const float*)d_in[4];
  const float* Wih0b = (const float*)d_in[5];
  const float* Whh0b = (const float*)d_in[6];
  const float* bih0b = (const float*)d_in[7];
  const float* bhh0b = (const float*)d_in[8];
  const float* Wih1f = (const float*)d_in[9];
  const float* Whh1f = (const float*)d_in[10];
  const float* bih1f = (const float*)d_in[11];
  const float* bhh1f = (const float*)d_in[12];
  const float* Wih1b = (const float*)d_in[13];
  const float* Whh1b = (const float*)d_in[14];
  const float* bih1b = (const float*)d_in[15];
  const float* bhh1b = (const float*)d_in[16];
  const float* fc1W  = (const float*)d_in[17];
  const float* fc1b  = (const float*)d_in[18];
  const float* fc2W  = (const float*)d_in[19];
  const float* fc2b  = (const float*)d_in[20];
  float* out = (float*)d_out;

  unsigned short* y0 = (unsigned short*)d_ws;                       // 134,217,728 B
  float* hT = (float*)((char*)d_ws + (size_t)1024 * TT * 128 * 2);

  dim3 grid(128, 2), block(512);
  lstm_l0<<<grid, block, 0, stream>>>(x, Wih0f, Whh0f, bih0f, bhh0f,
                                      Wih0b, Whh0b, bih0b, bhh0b, y0);
  lstm_l1<<<grid, block, 0, stream>>>(y0, Wih1f, Whh1f, bih1f, bhh1f,
                                      Wih1b, Whh1b, bih1b, bhh1b, hT);
  fc_kernel<<<dim3(256), dim3(256), 0, stream>>>(hT, fc1W, fc1b, fc2W, fc2b, out);
}